// Round 9
// baseline (280.336 us; speedup 1.0000x reference)
//
#include <hip/hip_runtime.h>

// DirectInterpGNN — segment-sum over 16M edges into 500K vertices, coef, gather.
// Round 9: round-8 counters: scatter_k 157us dominant; same dur cold vs replay
// (not BW-bound); 2 LDS atomics/edge + 256-wide scan + 6 barriers/subchunk.
// Fix: place-only scatter (1 LDS atomic/edge) into fixed-capacity per-bin
// stage slots (CAP=16, overflow ~0.3% -> direct global write at cur[b]+slot,
// disjoint), scan removed; register double-buffer prefetch of next subchunk.
// Order within bins becomes schedule-dependent, but u64 fixed-point
// accumulation is order-independent -> deterministic output.
//
// ws: coef[nv] | bin_total | bin_base | bh[NBLK*BINS] | partial[BINS*SPLIT*VPB]u64
//     | rec[ne]*8B | ah[ne]*2B

#define BINS 256
#define VSHIFT 11
#define VPB 2048         // vertices per bin = 1<<VSHIFT
#define NBLK 1024        // partition blocks
#define BT 256           // threads (scans, accum_part, coef, finalize)
#define SBT 512          // threads (hist, scatter)
#define SUB 2048         // edges per sub-chunk (LDS-staged)
#define SPLIT 8          // record slices per bin in accum
#define CAP 16           // staged slots per bin per sub-chunk

#define SC_A 524288.0f    // 2^19 (a in [0.1,1.1] -> ni <= 577K)
#define SC_D 4194304.0f   // 2^22 (d in [0.001,1.34] -> di <= 5.6M)

typedef unsigned int u32;
typedef unsigned short u16;
typedef unsigned long long u64;

static __device__ __forceinline__ u32 f2h(float x) {
    _Float16 h = (_Float16)x; u16 u; __builtin_memcpy(&u, &h, 2); return (u32)u;
}
static __device__ __forceinline__ float h2f(u32 u) {
    u16 v = (u16)u; _Float16 h; __builtin_memcpy(&h, &v, 2); return (float)h;
}

// ---------------- main path ----------------

__global__ void hist_k(const int* __restrict__ src, int ne, int chunk,
                       u32* __restrict__ bh) {
    __shared__ u32 h[BINS];
    for (int j = threadIdx.x; j < BINS; j += SBT) h[j] = 0;
    __syncthreads();
    int lo = blockIdx.x * chunk;            // chunk multiple of SUB -> 4-aligned
    int hi = min(ne, lo + chunk);
    int n = hi - lo;
    int ngroups = (n + 3) >> 2;
    for (int g = threadIdx.x; g < ngroups; g += SBT) {
        int i = lo + (g << 2);
        if (i + 3 < hi) {
            int4 s = *reinterpret_cast<const int4*>(src + i);
            atomicAdd(&h[((u32)s.x) >> VSHIFT], 1u);
            atomicAdd(&h[((u32)s.y) >> VSHIFT], 1u);
            atomicAdd(&h[((u32)s.z) >> VSHIFT], 1u);
            atomicAdd(&h[((u32)s.w) >> VSHIFT], 1u);
        } else {
            for (int j = i; j < hi; ++j)
                atomicAdd(&h[((u32)src[j]) >> VSHIFT], 1u);
        }
    }
    __syncthreads();
    for (int j = threadIdx.x; j < BINS; j += SBT)
        bh[(size_t)blockIdx.x * BINS + j] = h[j];
}

// per-bin column scan over NBLK block counts -> exclusive offsets (in place)
// + bin_total. grid = BINS, block = BT
__global__ void scan_col_k(u32* __restrict__ bh, u32* __restrict__ bin_total) {
    const int IT = NBLK / BT;   // 4
    int bin = blockIdx.x, t = threadIdx.x;
    u32 v[IT];
    u32 tsum = 0;
    #pragma unroll
    for (int k = 0; k < IT; ++k) {
        v[k] = bh[(size_t)(IT * t + k) * BINS + bin];
        tsum += v[k];
    }
    int lane = t & 63, wv = t >> 6;
    u32 inc = tsum;
    #pragma unroll
    for (int d = 1; d < 64; d <<= 1) {
        u32 y = __shfl_up(inc, d);
        if (lane >= d) inc += y;
    }
    __shared__ u32 wsum[BT / 64];
    if (lane == 63) wsum[wv] = inc;
    __syncthreads();
    u32 wbase = 0;
    for (int w = 0; w < wv; ++w) wbase += wsum[w];
    u32 run = wbase + inc - tsum;   // exclusive base for this thread
    #pragma unroll
    for (int k = 0; k < IT; ++k) {
        u32 c = v[k];
        bh[(size_t)(IT * t + k) * BINS + bin] = run;
        run += c;
    }
    if (t == BT - 1) bin_total[bin] = run;
}

// exclusive scan over BINS totals -> bin_base[0..BINS]. single block, BT>=BINS.
__global__ void scan_bins_k(const u32* __restrict__ bin_total,
                            u32* __restrict__ bin_base) {
    int t = threadIdx.x;
    u32 a0 = (t < BINS) ? bin_total[t] : 0;
    int lane = t & 63, wv = t >> 6;
    u32 inc = a0;
    #pragma unroll
    for (int d = 1; d < 64; d <<= 1) {
        u32 y = __shfl_up(inc, d);
        if (lane >= d) inc += y;
    }
    __shared__ u32 wsum[BT / 64];
    if (lane == 63) wsum[wv] = inc;
    __syncthreads();
    u32 wbase = 0;
    for (int w = 0; w < wv; ++w) wbase += wsum[w];
    if (t < BINS) bin_base[t] = wbase + inc - a0;
    if (t == BINS - 1) bin_base[BINS] = wbase + inc;  // == ne
}

__global__ __launch_bounds__(SBT, 2)
void scatter_k(const float* __restrict__ eattr,
               const int* __restrict__ src,
               const u32* __restrict__ bh,
               const u32* __restrict__ bin_base,
               uint2* __restrict__ rec,
               u16* __restrict__ ah,
               int ne, int chunk) {
    __shared__ u32 cur[BINS];            // running global cursor per bin
    __shared__ u32 cnt[BINS];            // per-sub-chunk allocation counter
    __shared__ uint2 stage[BINS * CAP];  // 32 KB
    int t = threadIdx.x;
    int lo = blockIdx.x * chunk;         // chunk is a multiple of SUB
    int hi = min(ne, lo + chunk);
    if (lo >= hi) return;
    for (int j = t; j < BINS; j += SBT)
        cur[j] = bin_base[j] + bh[(size_t)blockIdx.x * BINS + j];

    // register double buffer: er = flat [A0 S0 v0 A1 S1 v1 A2 S2 v2 A3 S3 v3]
    float erA[12], erB[12];
    int srA[4], srB[4];

    auto LOADV = [&](int base, float* er, int* sr) {
        int o = t << 2;
        int n = min(hi - base, SUB);
        int i = base + o;
        if (o + 3 < n) {
            int4 s4 = *reinterpret_cast<const int4*>(src + i);
            sr[0] = s4.x; sr[1] = s4.y; sr[2] = s4.z; sr[3] = s4.w;
            const float4* ea = reinterpret_cast<const float4*>(eattr + 3ll * i);
            float4 w0 = ea[0], w1 = ea[1], w2 = ea[2];
            er[0] = w0.x; er[1] = w0.y; er[2]  = w0.z; er[3]  = w0.w;
            er[4] = w1.x; er[5] = w1.y; er[6]  = w1.z; er[7]  = w1.w;
            er[8] = w2.x; er[9] = w2.y; er[10] = w2.z; er[11] = w2.w;
        } else {
            #pragma unroll
            for (int j = 0; j < 4; ++j) {
                if (o + j < n) {
                    sr[j] = src[i + j];
                    er[3 * j]     = eattr[3ll * (i + j)];
                    er[3 * j + 1] = eattr[3ll * (i + j) + 1];
                    er[3 * j + 2] = eattr[3ll * (i + j) + 2];
                }
            }
        }
    };

    auto PLACE = [&](int base, float* er, int* sr) {
        int o = t << 2;
        int n = min(hi - base, SUB);
        ushort4 hv;
        u16* hp = &hv.x;
        #pragma unroll
        for (int j = 0; j < 4; ++j) {
            if (o + j < n) {
                u32 s = (u32)sr[j];
                float a = er[3 * j];
                float d = a * er[3 * j + 1] * er[3 * j + 2];
                u32 ni = __float2uint_rn(a * SC_A);
                u32 di = __float2uint_rn(d * SC_D);
                u32 b = s >> VSHIFT;
                uint2 pay = make_uint2(di, (ni << VSHIFT) | (s & (VPB - 1)));
                hp[j] = (u16)f2h(a);
                u32 slot = atomicAdd(&cnt[b], 1u);
                if (slot < CAP) stage[(b << 4) | slot] = pay;
                else rec[cur[b] + slot] = pay;   // rare (~0.3%), disjoint from staged
            }
        }
        if (o + 3 < n) {
            *reinterpret_cast<ushort4*>(ah + base + o) = hv;
        } else {
            #pragma unroll
            for (int j = 0; j < 4; ++j)
                if (o + j < n) ah[base + o + j] = hp[j];
        }
    };

    LOADV(lo, erA, srA);
    for (int base = lo; base < hi; base += SUB) {
        if (t < BINS) cnt[t] = 0;
        __syncthreads();
        PLACE(base, erA, srA);
        if (base + SUB < hi) LOADV(base + SUB, erB, srB);   // prefetch
        __syncthreads();
        // flush staged slots: consecutive j -> consecutive global addresses
        #pragma unroll
        for (int r = 0; r < (BINS * CAP) / SBT; ++r) {      // 8
            int j = t + r * SBT;
            u32 b = (u32)j >> 4, s = (u32)j & 15u;
            u32 c = cnt[b];
            if (s < min(c, (u32)CAP)) rec[cur[b] + s] = stage[j];
        }
        __syncthreads();
        if (t < BINS) cur[t] += cnt[t];
        #pragma unroll
        for (int j = 0; j < 12; ++j) erA[j] = erB[j];
        #pragma unroll
        for (int j = 0; j < 4; ++j) srA[j] = srB[j];
    }
}

// one block per (bin, slice); single u64 LDS atomic per record
__global__ void accum_part_k(const uint2* __restrict__ rec,
                             const u32* __restrict__ bin_base,
                             u64* __restrict__ partial) {
    __shared__ u64 acc[VPB];   // 16 KB
    int bin = blockIdx.x / SPLIT;
    int q   = blockIdx.x % SPLIT;
    for (int l = threadIdx.x; l < VPB; l += BT) acc[l] = 0ull;
    __syncthreads();
    u32 s0 = bin_base[bin], s1 = bin_base[bin + 1];
    u32 cnt = s1 - s0;
    u32 ra = s0 + (u32)((u64)cnt * q / SPLIT);
    u32 rb = s0 + (u32)((u64)cnt * (q + 1) / SPLIT);
    for (u32 r = ra + threadIdx.x; r < rb; r += BT) {
        uint2 qq = rec[r];
        // num field: ni @2^19 -> <<3 for 2^22 scale, at bit 32 => <<35
        u64 add = ((u64)(qq.y >> VSHIFT) << 35) | (u64)qq.x;
        atomicAdd(&acc[qq.y & (VPB - 1)], add);
    }
    __syncthreads();
    u64* po = partial + (size_t)blockIdx.x * VPB;
    for (int l = threadIdx.x; l < VPB; l += BT) po[l] = acc[l];
}

__global__ void coef_part_k(const u64* __restrict__ partial,
                            const float* __restrict__ vattr,
                            float* __restrict__ coef, int nv) {
    int v = blockIdx.x * blockDim.x + threadIdx.x;
    int stride = gridDim.x * blockDim.x;
    for (; v < nv; v += stride) {
        int bin = v >> VSHIFT, l = v & (VPB - 1);
        size_t base = ((size_t)bin * SPLIT << VSHIFT) + l;
        float num = 0.f, den = 0.f;
        #pragma unroll
        for (int sp = 0; sp < SPLIT; ++sp) {
            u64 p = partial[base + ((size_t)sp << VSHIFT)];
            num += (float)(u32)(p >> 32);
            den += (float)(u32)p;
        }
        // both fields at scale 2^22; gammabar = num/den is scale-free
        float2 va = reinterpret_cast<const float2*>(vattr)[v];  // (A_ii, C_i)
        float gam = num / den;   // NaN only for edgeless vertices; never gathered
        coef[v] = (1.0f - va.y) * (-gam / va.x);
    }
}

// ---------------- fallback path (ws too small): packed u64 atomics ----------------

#define FPSCALE 8388608.0f      // 2^23
#define FPINV   (1.0f / 8388608.0f)

__global__ void zero_u64(u64* __restrict__ p, int n) {
    int i = blockIdx.x * blockDim.x + threadIdx.x;
    int stride = gridDim.x * blockDim.x;
    for (; i < n; i += stride) p[i] = 0ull;
}

__global__ void accum_packed(const float* __restrict__ eattr,
                             const int* __restrict__ src,
                             u64* __restrict__ accp,
                             u16* __restrict__ ah, int ne) {
    int t = blockIdx.x * blockDim.x + threadIdx.x;
    int stride = gridDim.x * blockDim.x;
    for (int i = t; i < ne; i += stride) {
        float a = eattr[3ll * i];
        float d = a * eattr[3ll * i + 1] * eattr[3ll * i + 2];
        u32 ni = (u32)__float2uint_rn(a * FPSCALE);
        u32 di = (u32)__float2uint_rn(d * FPSCALE);
        atomicAdd(&accp[(u32)src[i]], ((u64)ni << 32) | (u64)di);
        if (ah) ah[i] = (u16)f2h(a);
    }
}

__global__ void coef_packed(const float* __restrict__ vattr,
                            const u64* __restrict__ accp,
                            float* __restrict__ coef, int nv) {
    int v = blockIdx.x * blockDim.x + threadIdx.x;
    int stride = gridDim.x * blockDim.x;
    for (; v < nv; v += stride) {
        u64 a = accp[v];
        float num = (float)(u32)(a >> 32) * FPINV;
        float den = (float)(u32)a * FPINV;
        float2 va = reinterpret_cast<const float2*>(vattr)[v];
        coef[v] = (1.0f - va.y) * (-(num / den) / va.x);
    }
}

// ---------------- finalize (shared) ----------------

__global__ void finalize(const u16* __restrict__ ah,
                         const float* __restrict__ edge_attr,
                         const int* __restrict__ src,
                         const float* __restrict__ coef,
                         float* __restrict__ out, int ne4, int n_edges) {
    int t = blockIdx.x * blockDim.x + threadIdx.x;
    int stride = gridDim.x * blockDim.x;
    for (int i = t; i < ne4; i += stride) {
        int4 s = reinterpret_cast<const int4*>(src)[i];
        float4 A;
        if (ah) {
            ushort4 h = reinterpret_cast<const ushort4*>(ah)[i];
            A.x = h2f(h.x); A.y = h2f(h.y); A.z = h2f(h.z); A.w = h2f(h.w);
        } else {
            const float* e = edge_attr + 12ll * i;
            A.x = e[0]; A.y = e[3]; A.z = e[6]; A.w = e[9];
        }
        float4 w;
        w.x = coef[s.x] * A.x;
        w.y = coef[s.y] * A.y;
        w.z = coef[s.z] * A.z;
        w.w = coef[s.w] * A.w;
        reinterpret_cast<float4*>(out)[i] = w;
    }
    for (int e = 4 * ne4 + t; e < n_edges; e += stride) {
        float Ae = ah ? h2f(ah[e]) : edge_attr[3ll * e];
        out[e] = coef[src[e]] * Ae;
    }
}

extern "C" void kernel_launch(void* const* d_in, const int* in_sizes, int n_in,
                              void* d_out, int out_size, void* d_ws, size_t ws_size,
                              hipStream_t stream) {
    const float* vattr = (const float*)d_in[0];   // (nv, 2)
    const float* eattr = (const float*)d_in[1];   // (ne, 3)
    const int*   pair  = (const int*)d_in[2];     // (2, ne)
    int nv = in_sizes[0] / 2;
    int ne = in_sizes[1] / 3;
    const int* src = pair;                         // row 0
    float* out = (float*)d_out;

    int ne4 = ne / 4;
    auto capped = [](long long want, int cap) {
        return (int)(want < cap ? (want > 1 ? want : 1) : cap);
    };
    int fgrid = capped(((long long)ne4 + BT - 1) / BT, 4096);

    // main-path ws layout
    size_t off = 0;
    float* coef = (float*)((char*)d_ws + off); off += (size_t)nv * 4;
    off = (off + 255) & ~(size_t)255;
    u32* bin_total = (u32*)((char*)d_ws + off); off += (size_t)BINS * 4;
    u32* bin_base  = (u32*)((char*)d_ws + off); off += (size_t)(BINS + 1) * 4;
    off = (off + 255) & ~(size_t)255;
    u32* bh  = (u32*)((char*)d_ws + off); off += (size_t)NBLK * BINS * 4;
    off = (off + 255) & ~(size_t)255;
    u64* partial = (u64*)((char*)d_ws + off); off += ((size_t)BINS * SPLIT << VSHIFT) * 8;
    off = (off + 255) & ~(size_t)255;
    uint2* rec = (uint2*)((char*)d_ws + off); off += 8ull * ne;
    off = (off + 255) & ~(size_t)255;
    u16* ah = (u16*)((char*)d_ws + off); off += 2ull * ne;
    // chunk: multiple of SUB so sub-chunk bases stay 4-aligned for int4/float4
    long long chunk_ll = ((((long long)ne + NBLK - 1) / NBLK) + SUB - 1) / SUB * SUB;
    bool main_ok = ws_size >= off && nv <= (BINS << VSHIFT) &&
                   chunk_ll * NBLK < 2147000000ll;
    int chunk = (int)chunk_ll;

    if (main_ok) {
        hist_k<<<NBLK, SBT, 0, stream>>>(src, ne, chunk, bh);
        scan_col_k<<<BINS, BT, 0, stream>>>(bh, bin_total);
        scan_bins_k<<<1, BT, 0, stream>>>(bin_total, bin_base);
        scatter_k<<<NBLK, SBT, 0, stream>>>(eattr, src, bh, bin_base, rec, ah, ne, chunk);
        accum_part_k<<<BINS * SPLIT, BT, 0, stream>>>(rec, bin_base, partial);
        coef_part_k<<<capped(((long long)nv + BT - 1) / BT, 2048), BT, 0, stream>>>(partial, vattr, coef, nv);
        finalize<<<fgrid, BT, 0, stream>>>(ah, eattr, src, coef, out, ne4, ne);
    } else {
        // fallback: packed u64 atomics
        u64* accp = (u64*)d_ws;
        float* fcoef = (float*)(accp + nv);
        size_t fb_base = (size_t)nv * 12;
        fb_base = (fb_base + 255) & ~(size_t)255;
        u16* fah = nullptr;
        if (ws_size >= fb_base + 2ull * ne)
            fah = (u16*)((char*)d_ws + fb_base);
        int zgrid = capped(((long long)nv + BT - 1) / BT, 2048);
        int agrid = capped(((long long)ne + BT - 1) / BT, 4096);
        int cgrid = capped(((long long)nv + BT - 1) / BT, 2048);
        zero_u64<<<zgrid, BT, 0, stream>>>(accp, nv);
        accum_packed<<<agrid, BT, 0, stream>>>(eattr, src, accp, fah, ne);
        coef_packed<<<cgrid, BT, 0, stream>>>(vattr, accp, fcoef, nv);
        finalize<<<fgrid, BT, 0, stream>>>(fah, eattr, src, fcoef, out, ne4, ne);
    }
}